// Round 6
// baseline (1602.032 us; speedup 1.0000x reference)
//
#include <hip/hip_runtime.h>
#include <hip/hip_bf16.h>

// B=32, C=256, H=36, W=64, n=4096.  P = H*W = 2304.  NCOL = B*C = 8192.
#define P_HW   2304
#define NG     4096
#define NCOL   8192
#define KDIM   P_HW
#define NT     72          // K-tiles of 32: 2304/32

typedef __bf16 bf16x8 __attribute__((ext_vector_type(8)));
typedef float  f32x4  __attribute__((ext_vector_type(4)));

__device__ __forceinline__ unsigned short f2bf(float f) {
    union { float f; unsigned int u; } x; x.f = f;
    unsigned int r = x.u + 0x7FFFu + ((x.u >> 16) & 1u);   // RNE
    return (unsigned short)(r >> 16);
}

// ---------------------------------------------------------------------------
// Fused prep: UNCHANGED from baseline.
// ---------------------------------------------------------------------------
__global__ __launch_bounds__(256) void prep_kernel(
    const float* __restrict__ feat,
    const float* __restrict__ mu,
    const float* __restrict__ logsx,
    const float* __restrict__ logsy,
    const float* __restrict__ rho,
    unsigned short* __restrict__ F,
    unsigned short* __restrict__ G,
    float* __restrict__ out) {
    const int bid = blockIdx.x;
    const int tid = threadIdx.x;
    if (bid < 9216) {
        const size_t i = ((size_t)bid * 256 + tid) * 8;
        const float4 v0 = *(const float4*)(feat + i);
        const float4 v1 = *(const float4*)(feat + i + 4);
        union { unsigned short s[8]; uint4 q; } o;
        o.s[0] = f2bf(v0.x); o.s[1] = f2bf(v0.y); o.s[2] = f2bf(v0.z); o.s[3] = f2bf(v0.w);
        o.s[4] = f2bf(v1.x); o.s[5] = f2bf(v1.y); o.s[6] = f2bf(v1.z); o.s[7] = f2bf(v1.w);
        *(uint4*)(F + i) = o.q;
    } else if (bid < 13312) {
        const int n = bid - 9216;
        const float mux = mu[2 * n], muy = mu[2 * n + 1];
        const float sx = __expf(logsx[n]) + 1e-6f;
        const float sy = __expf(logsy[n]) + 1e-6f;
        const float r  = tanhf(rho[n]);
        const float inv_den = 1.0f / (2.0f * (1.0f - r * r + 1e-6f));
        const float isx = 1.0f / sx, isy = 1.0f / sy;
        for (int base = tid * 8; base < P_HW; base += 2048) {
            const int h = base >> 6, w0 = base & 63;      // W = 64
            const float Y  = -1.0f + (float)h * (2.0f / 35.0f);
            const float yc = (Y - muy) * isy;
            union { unsigned short s[8]; uint4 q; } o;
#pragma unroll
            for (int j = 0; j < 8; ++j) {
                const float X  = -1.0f + (float)(w0 + j) * (2.0f / 63.0f);
                const float xc = (X - mux) * isx;
                const float A  = xc * xc + yc * yc - 2.0f * r * xc * yc;
                o.s[j] = f2bf(__expf(-A * inv_den));
            }
            *(uint4*)&G[(size_t)n * P_HW + base] = o.q;
        }
    } else {
        const size_t i = ((size_t)(bid - 13312) * 256 + tid) * 8;
        const float4 z = {0.f, 0.f, 0.f, 0.f};
        *(float4*)(out + i)     = z;
        *(float4*)(out + i + 4) = z;
    }
}

// ---------------------------------------------------------------------------
// GEMM v6: 2 blocks/CU for cross-block pipe overlap.  R5 post-mortem: with
// 1 block/CU (128 KB ring) ALL resident waves share one barrier group =>
// LDS-read convoy (1152 cyc) and MFMA convoy (1242 cyc) run serially —
// 2664 cyc/tile measured, MfmaUtil stuck ~42% regardless of intra-block
// schedule (v4 free-run == v5 phase-split).  Fix: ring 4->2 (64 KB LDS)
// => 2 blocks/CU with INDEPENDENT barriers => anti-phased blocks overlap
// pipes hardware-side (m114 mechanism; m97's 3-block overlap).  Prefetch
// depth 1: stage t+1 at tile START (~2400 cyc lead on L2-resident data),
// vmcnt(0)+barrier at tile end is then nearly free, and the other block
// covers the residual.  setprio(1) now arbitrates between anti-phased
// blocks (m191 regime).  Swizzle/epilogue unchanged.
// ---------------------------------------------------------------------------
__device__ __forceinline__ void async16(const void* g, void* l) {
    __builtin_amdgcn_global_load_lds(
        (__attribute__((address_space(1))) void*)(unsigned long long)g,
        (__attribute__((address_space(3))) void*)(unsigned int)(unsigned long long)l,
        16, 0, 0);
}

__global__ __launch_bounds__(512, 4) void gemm_fused(
    const unsigned short* __restrict__ G,   // [NG][K] bf16
    const unsigned short* __restrict__ F,   // [NCOL][K] bf16
    const float* __restrict__ weight,       // [NG][256] fp32
    float* __restrict__ out)                // [32][NG] fp32
{
    // 2 ring buffers; each: A[256][32] + B[256][32] bf16 (32 KB).
    // LDS slot (r, cp) holds global chunk c = cp ^ ((r>>1)&3)  [XOR swizzle].
    __shared__ __align__(16) unsigned short lds[2 * 16384];

    const int tid  = threadIdx.x;            // 0..511
    const int lane = tid & 63;
    const int wid  = tid >> 6;               // 0..7
    const int wr   = wid >> 2;               // 0..1  (M half: 128 rows)
    const int wc   = wid & 3;                // 0..3  (N quarter: 64 cols)
    const int quad = lane >> 4, m = lane & 15;

    const int rowBase = blockIdx.y * 256;    // over NG
    const int colBase = blockIdx.x * 256;    // over NCOL (= b*256, full C range)

    // Staging: thread t, round i: slot s=i*512+t -> r=i*128+(t>>2), cp=t&3;
    // global chunk c = cp ^ ((r>>1)&3) = (t&3) ^ ((t>>3)&3)   [i-invariant]
    const int rA = tid >> 2;
    const int cA = (tid & 3) ^ ((tid >> 3) & 3);
    const unsigned short* pA = G + (size_t)(rowBase + rA) * KDIM + cA * 8;
    const unsigned short* pB = F + (size_t)(colBase + rA) * KDIM + cA * 8;

    // ds_read: row = band + m (band mult of 16), chunk cp = quad ^ ((m>>1)&3)
    const int sw   = (quad ^ ((m >> 1) & 3)) * 8;
    const int aoff = (wr * 128 + m) * 32 + sw;
    const int boff = (wc * 64  + m) * 32 + sw;

    f32x4 acc[8][4];
#pragma unroll
    for (int i = 0; i < 8; ++i)
#pragma unroll
        for (int j = 0; j < 4; ++j)
            acc[i][j] = (f32x4){0.f, 0.f, 0.f, 0.f};

    // Prologue: stage tile 0 into buf0, drain, sync.
    async16(pA,              &lds[tid * 8]);
    async16(pA + 128 * KDIM, &lds[4096 + tid * 8]);
    async16(pB,              &lds[8192 + tid * 8]);
    async16(pB + 128 * KDIM, &lds[12288 + tid * 8]);
    asm volatile("s_waitcnt vmcnt(0)" ::: "memory");
    __builtin_amdgcn_s_barrier();
    asm volatile("" ::: "memory");

    // Main loop: tile t from buf t&1; stage tile t+1 into buf (t+1)&1 (the
    // buffer consumed two tiles ago — all reads done at the last barrier).
    // x2 unroll keeps LDS bases static.  Wrap stages garbage into the
    // consumed buffer on the final tile; drained before the epilogue.
    for (int tt = 0; tt < NT; tt += 2) {
#pragma unroll
        for (int u = 0; u < 2; ++u) {
            const int t   = tt + u;
            const int bo  = u * 16384;           // static
            const int wbo = (u ^ 1) * 16384;     // static
            int w = t + 1;
            if (w >= NT) w -= NT;
            const unsigned short* pAw = pA + w * 32;
            const unsigned short* pBw = pB + w * 32;

            // issue next-tile staging first: max lead time before the wait
            async16(pAw,              &lds[wbo + tid * 8]);
            async16(pAw + 128 * KDIM, &lds[wbo + 4096 + tid * 8]);
            async16(pBw,              &lds[wbo + 8192 + tid * 8]);
            async16(pBw + 128 * KDIM, &lds[wbo + 12288 + tid * 8]);

            // 12 ds_reads + 32 MFMA; compiler interleaves via counted lgkmcnt
            bf16x8 a[8], b[4];
#pragma unroll
            for (int j = 0; j < 4; ++j)
                b[j] = *(const bf16x8*)&lds[bo + 8192 + boff + j * 512];
#pragma unroll
            for (int i = 0; i < 8; ++i)
                a[i] = *(const bf16x8*)&lds[bo + aoff + i * 512];

            __builtin_amdgcn_s_setprio(1);
#pragma unroll
            for (int i = 0; i < 8; ++i)
#pragma unroll
                for (int j = 0; j < 4; ++j)
                    acc[i][j] = __builtin_amdgcn_mfma_f32_16x16x32_bf16(a[i], b[j], acc[i][j], 0, 0, 0);
            __builtin_amdgcn_s_setprio(0);

            // t+1's 4 loads were issued ~a full tile ago -> near-free drain;
            // barrier then publishes the landed tile to all waves.
            asm volatile("s_waitcnt vmcnt(0)" ::: "memory");
            __builtin_amdgcn_s_barrier();
            asm volatile("" ::: "memory");
        }
    }

    __syncthreads();

    // Epilogue: out[b][n] = sum_c pooled[n][b*256+c] * weight[n][c].
    float* red = (float*)lds;                // [4 wc][256 n_local]
    const int cwbase = wc * 64 + m;
#pragma unroll
    for (int i = 0; i < 8; ++i) {
#pragma unroll
        for (int reg = 0; reg < 4; ++reg) {
            const int nloc = wr * 128 + i * 16 + quad * 4 + reg;
            const float* wrow = weight + (size_t)(rowBase + nloc) * 256 + cwbase;
            float s = 0.f;
#pragma unroll
            for (int j = 0; j < 4; ++j)
                s += acc[i][j][reg] * wrow[j * 16];
            s += __shfl_xor(s, 1);
            s += __shfl_xor(s, 2);
            s += __shfl_xor(s, 4);
            s += __shfl_xor(s, 8);
            if (m == 0)
                red[wc * 256 + nloc] = s;
        }
    }
    __syncthreads();
    if (tid < 256) {
        const float s = red[tid] + red[256 + tid] + red[512 + tid] + red[768 + tid];
        out[(size_t)blockIdx.x * NG + rowBase + tid] = s;
    }
}

// ---------------------------------------------------------------------------
extern "C" void kernel_launch(void* const* d_in, const int* in_sizes, int n_in,
                              void* d_out, int out_size, void* d_ws, size_t ws_size,
                              hipStream_t stream) {
    const float* feat   = (const float*)d_in[0];
    const float* mu     = (const float*)d_in[1];
    const float* logsx  = (const float*)d_in[2];
    const float* logsy  = (const float*)d_in[3];
    const float* rho    = (const float*)d_in[4];
    const float* weight = (const float*)d_in[5];
    float* out = (float*)d_out;

    unsigned short* Gbuf = (unsigned short*)d_ws;                  // 4096*2304*2 B
    unsigned short* Fbuf = Gbuf + (size_t)NG * P_HW;               // 8192*2304*2 B

    hipLaunchKernelGGL(prep_kernel, dim3(13376), dim3(256), 0, stream,
                       feat, mu, logsx, logsy, rho, Fbuf, Gbuf, out);

    hipLaunchKernelGGL(gemm_fused, dim3(NCOL / 256, NG / 256), dim3(512), 0, stream,
                       Gbuf, Fbuf, weight, out);
}

// Round 7
// 269.853 us; speedup vs baseline: 5.9367x; 5.9367x over previous
//
#include <hip/hip_runtime.h>
#include <hip/hip_bf16.h>

// B=32, C=256, H=36, W=64, n=4096.  P = H*W = 2304.  NCOL = B*C = 8192.
#define P_HW   2304
#define NG     4096
#define NCOL   8192
#define KDIM   P_HW
#define NKT    36          // K-tiles of 64: 2304/64

typedef __bf16 bf16x8 __attribute__((ext_vector_type(8)));
typedef float  f32x4  __attribute__((ext_vector_type(4)));

__device__ __forceinline__ unsigned short f2bf(float f) {
    union { float f; unsigned int u; } x; x.f = f;
    unsigned int r = x.u + 0x7FFFu + ((x.u >> 16) & 1u);   // RNE
    return (unsigned short)(r >> 16);
}

// ---------------------------------------------------------------------------
// Fused prep: UNCHANGED from baseline.
// ---------------------------------------------------------------------------
__global__ __launch_bounds__(256) void prep_kernel(
    const float* __restrict__ feat,
    const float* __restrict__ mu,
    const float* __restrict__ logsx,
    const float* __restrict__ logsy,
    const float* __restrict__ rho,
    unsigned short* __restrict__ F,
    unsigned short* __restrict__ G,
    float* __restrict__ out) {
    const int bid = blockIdx.x;
    const int tid = threadIdx.x;
    if (bid < 9216) {
        const size_t i = ((size_t)bid * 256 + tid) * 8;
        const float4 v0 = *(const float4*)(feat + i);
        const float4 v1 = *(const float4*)(feat + i + 4);
        union { unsigned short s[8]; uint4 q; } o;
        o.s[0] = f2bf(v0.x); o.s[1] = f2bf(v0.y); o.s[2] = f2bf(v0.z); o.s[3] = f2bf(v0.w);
        o.s[4] = f2bf(v1.x); o.s[5] = f2bf(v1.y); o.s[6] = f2bf(v1.z); o.s[7] = f2bf(v1.w);
        *(uint4*)(F + i) = o.q;
    } else if (bid < 13312) {
        const int n = bid - 9216;
        const float mux = mu[2 * n], muy = mu[2 * n + 1];
        const float sx = __expf(logsx[n]) + 1e-6f;
        const float sy = __expf(logsy[n]) + 1e-6f;
        const float r  = tanhf(rho[n]);
        const float inv_den = 1.0f / (2.0f * (1.0f - r * r + 1e-6f));
        const float isx = 1.0f / sx, isy = 1.0f / sy;
        for (int base = tid * 8; base < P_HW; base += 2048) {
            const int h = base >> 6, w0 = base & 63;      // W = 64
            const float Y  = -1.0f + (float)h * (2.0f / 35.0f);
            const float yc = (Y - muy) * isy;
            union { unsigned short s[8]; uint4 q; } o;
#pragma unroll
            for (int j = 0; j < 8; ++j) {
                const float X  = -1.0f + (float)(w0 + j) * (2.0f / 63.0f);
                const float xc = (X - mux) * isx;
                const float A  = xc * xc + yc * yc - 2.0f * r * xc * yc;
                o.s[j] = f2bf(__expf(-A * inv_den));
            }
            *(uint4*)&G[(size_t)n * P_HW + base] = o.q;
        }
    } else {
        const size_t i = ((size_t)(bid - 13312) * 256 + tid) * 8;
        const float4 z = {0.f, 0.f, 0.f, 0.f};
        *(float4*)(out + i)     = z;
        *(float4*)(out + i + 4) = z;
    }
}

// ---------------------------------------------------------------------------
// GEMM v7: faithful m201 8-phase port.  256x256 tile, BK=64, 8 waves
// (2M x 4N), double-buffered 128 KB LDS, 8 phases per 2 K-tiles.
// Per phase: {ds_read one register subtile; stage 2 quarter-gloads;
// [vmcnt(6) at P4/P8]; barrier; lgkmcnt(0); setprio(1); 16 MFMA (one
// C-quadrant); setprio(0); barrier}.  Staging granularity = 64-row
// quarter (1 gload/thread); each quarter staged exactly one phase after
// all waves finished reading it (barrier+lgkmcnt fence), so in-place
// streaming overwrite is race-free.  vmcnt(6) leaves the 3 newest
// quarters in flight; never drains to 0 in the loop (T3+T4).
// R6 lesson: launch_bounds(512,4) capped VGPR at 128 -> acc spilled to
// scratch (WRITE_SIZE 4.6 GB, VGPR=64).  (512,2) => 256-VGPR cap.
// BK=64 row = 128 B -> proven chunk^(row&7) swizzle (conflict-free, R1).
// ---------------------------------------------------------------------------
__device__ __forceinline__ void async16(const void* g, void* l) {
    __builtin_amdgcn_global_load_lds(
        (__attribute__((address_space(1))) void*)(unsigned long long)g,
        (__attribute__((address_space(3))) void*)(unsigned int)(unsigned long long)l,
        16, 0, 0);
}

__global__ __launch_bounds__(512, 2) void gemm_fused(
    const unsigned short* __restrict__ G,   // [NG][K] bf16
    const unsigned short* __restrict__ F,   // [NCOL][K] bf16
    const float* __restrict__ weight,       // [NG][256] fp32
    float* __restrict__ out)                // [32][NG] fp32
{
    // 2 buffers; each: A[256][64] + B[256][64] bf16 (64 KB).  Row = 128 B.
    // LDS slot (r, cp) holds global chunk c = cp ^ (r&7)  [XOR swizzle].
    __shared__ __align__(16) unsigned short lds[2 * 32768];

    const int tid  = threadIdx.x;            // 0..511
    const int lane = tid & 63;
    const int wid  = tid >> 6;               // 0..7
    const int wr   = wid >> 2;               // 0..1  (M half: 128 rows)
    const int wc   = wid & 3;                // 0..3  (N quarter: 64 cols)
    const int quad = lane >> 4, m = lane & 15;

    const int rowBase = blockIdx.y * 256;    // over NG
    const int colBase = blockIdx.x * 256;    // over NCOL (= b*256)

    // Staging: quarter q (64 rows) = 512 slots of 16B, 1/thread.
    // slot=tid: r = q*64 + (tid>>3), cp = tid&7, global chunk
    // c = cp ^ (r&7) = (tid&7) ^ ((tid>>3)&7)   [q-invariant].
    const int rS = tid >> 3;
    const int cS = (tid & 7) ^ (rS & 7);
    const unsigned short* pA = G + (size_t)(rowBase + rS) * KDIM + cS * 8;
    const unsigned short* pB = F + (size_t)(colBase + rS) * KDIM + cS * 8;

#define STG_A(buf, q, kt) async16(pA + (q) * 64 * KDIM + (kt) * 64, \
        &lds[(buf) * 32768 + (q) * 4096 + tid * 8])
#define STG_B(buf, q, kt) async16(pB + (q) * 64 * KDIM + (kt) * 64, \
        &lds[(buf) * 32768 + 16384 + (q) * 4096 + tid * 8])

    // ds_read: row = base + m, chunk = kk*4 + quad, swz chunk ^= (m&7)
    const int arow = (wr * 128 + m) * 64;
    const int brow = (wc * 64  + m) * 64;
    const int cs0  = ((quad)     ^ (m & 7)) * 8;   // kk=0
    const int cs1  = ((4 + quad) ^ (m & 7)) * 8;   // kk=1

    f32x4 acc[8][4];
#pragma unroll
    for (int i = 0; i < 8; ++i)
#pragma unroll
        for (int j = 0; j < 4; ++j)
            acc[i][j] = (f32x4){0.f, 0.f, 0.f, 0.f};

    // Prologue: tile0 (8 quarters) + tile1's first 6 (stream order P6,P7,P8)
    STG_A(0, 0, 0); STG_A(0, 1, 0); STG_A(0, 2, 0); STG_A(0, 3, 0);
    STG_B(0, 0, 0); STG_B(0, 1, 0); STG_B(0, 2, 0); STG_B(0, 3, 0);
    STG_A(1, 0, 1); STG_A(1, 2, 1);
    STG_B(1, 0, 1); STG_B(1, 1, 1);
    STG_A(1, 1, 1); STG_A(1, 3, 1);
    asm volatile("s_waitcnt vmcnt(6)" ::: "memory");
    __builtin_amdgcn_s_barrier();

#define MFMA_Q(IOFF, JOFF, AX, BX)                                         \
    __builtin_amdgcn_s_setprio(1);                                         \
    _Pragma("unroll")                                                      \
    for (int fi = 0; fi < 4; ++fi)                                         \
        _Pragma("unroll")                                                  \
        for (int fj = 0; fj < 2; ++fj)                                     \
            _Pragma("unroll")                                              \
            for (int kk = 0; kk < 2; ++kk)                                 \
                acc[fi + IOFF][fj + JOFF] =                                \
                    __builtin_amdgcn_mfma_f32_16x16x32_bf16(               \
                        AX[fi][kk], BX[fj][kk], acc[fi + IOFF][fj + JOFF], \
                        0, 0, 0);                                          \
    __builtin_amdgcn_s_setprio(0);

#define BARRIER_IN()  __builtin_amdgcn_s_barrier();                        \
                      asm volatile("s_waitcnt lgkmcnt(0)" ::: "memory");
#define BARRIER_OUT() __builtin_amdgcn_s_barrier();

    for (int it = 0; it < NKT / 2; ++it) {
        const int t = 2 * it;
        int k2 = t + 2; if (k2 >= NKT) k2 -= NKT;   // wrap: garbage into
        int k3 = t + 3; if (k3 >= NKT) k3 -= NKT;   // consumed regions
        bf16x8 a[4][2], blo[2][2], bhi[2][2];

        // ---- P1: tile t (buf0), Q(Mlo,Nlo).  Reads a_lo + b_lo (12). ----
#pragma unroll
        for (int fi = 0; fi < 4; ++fi) {
            a[fi][0] = *(const bf16x8*)&lds[arow + fi * 1024 + cs0];
            a[fi][1] = *(const bf16x8*)&lds[arow + fi * 1024 + cs1];
        }
#pragma unroll
        for (int fj = 0; fj < 2; ++fj) {
            blo[fj][0] = *(const bf16x8*)&lds[16384 + brow + fj * 1024 + cs0];
            blo[fj][1] = *(const bf16x8*)&lds[16384 + brow + fj * 1024 + cs1];
        }
        STG_B(1, 2, t + 1); STG_B(1, 3, t + 1);
        BARRIER_IN();
        MFMA_Q(0, 0, a, blo);
        BARRIER_OUT();

        // ---- P2: Q(Mlo,Nhi).  Reads b_hi (4). ----
#pragma unroll
        for (int fj = 0; fj < 2; ++fj) {
            bhi[fj][0] = *(const bf16x8*)&lds[16384 + brow + 2048 + fj * 1024 + cs0];
            bhi[fj][1] = *(const bf16x8*)&lds[16384 + brow + 2048 + fj * 1024 + cs1];
        }
        STG_A(0, 0, k2); STG_A(0, 2, k2);
        BARRIER_IN();
        MFMA_Q(0, 2, a, bhi);
        BARRIER_OUT();

        // ---- P3: Q(Mhi,Nhi).  Reads a_hi (8, overwrites a regs). ----
#pragma unroll
        for (int fi = 0; fi < 4; ++fi) {
            a[fi][0] = *(const bf16x8*)&lds[arow + 4096 + fi * 1024 + cs0];
            a[fi][1] = *(const bf16x8*)&lds[arow + 4096 + fi * 1024 + cs1];
        }
        STG_B(0, 0, k2); STG_B(0, 2, k2);
        BARRIER_IN();
        MFMA_Q(4, 2, a, bhi);
        BARRIER_OUT();

        // ---- P4: Q(Mhi,Nlo).  No reads.  vmcnt(6): tile t+1 landed. ----
        STG_A(0, 1, k2); STG_A(0, 3, k2);
        asm volatile("s_waitcnt vmcnt(6)" ::: "memory");
        BARRIER_IN();
        MFMA_Q(4, 0, a, blo);
        BARRIER_OUT();

        // ---- P5: tile t+1 (buf1), Q(Mlo,Nlo). ----
#pragma unroll
        for (int fi = 0; fi < 4; ++fi) {
            a[fi][0] = *(const bf16x8*)&lds[32768 + arow + fi * 1024 + cs0];
            a[fi][1] = *(const bf16x8*)&lds[32768 + arow + fi * 1024 + cs1];
        }
#pragma unroll
        for (int fj = 0; fj < 2; ++fj) {
            blo[fj][0] = *(const bf16x8*)&lds[32768 + 16384 + brow + fj * 1024 + cs0];
            blo[fj][1] = *(const bf16x8*)&lds[32768 + 16384 + brow + fj * 1024 + cs1];
        }
        STG_B(0, 1, k2); STG_B(0, 3, k2);
        BARRIER_IN();
        MFMA_Q(0, 0, a, blo);
        BARRIER_OUT();

        // ---- P6: Q(Mlo,Nhi). ----
#pragma unroll
        for (int fj = 0; fj < 2; ++fj) {
            bhi[fj][0] = *(const bf16x8*)&lds[32768 + 16384 + brow + 2048 + fj * 1024 + cs0];
            bhi[fj][1] = *(const bf16x8*)&lds[32768 + 16384 + brow + 2048 + fj * 1024 + cs1];
        }
        STG_A(1, 0, k3); STG_A(1, 2, k3);
        BARRIER_IN();
        MFMA_Q(0, 2, a, bhi);
        BARRIER_OUT();

        // ---- P7: Q(Mhi,Nhi). ----
#pragma unroll
        for (int fi = 0; fi < 4; ++fi) {
            a[fi][0] = *(const bf16x8*)&lds[32768 + arow + 4096 + fi * 1024 + cs0];
            a[fi][1] = *(const bf16x8*)&lds[32768 + arow + 4096 + fi * 1024 + cs1];
        }
        STG_B(1, 0, k3); STG_B(1, 1, k3);
        BARRIER_IN();
        MFMA_Q(4, 2, a, bhi);
        BARRIER_OUT();

        // ---- P8: Q(Mhi,Nlo).  vmcnt(6): tile t+2 landed. ----
        STG_A(1, 1, k3); STG_A(1, 3, k3);
        asm volatile("s_waitcnt vmcnt(6)" ::: "memory");
        BARRIER_IN();
        MFMA_Q(4, 0, a, blo);
        BARRIER_OUT();
    }

    // Drain the wrapped garbage prefetches before reusing LDS.
    asm volatile("s_waitcnt vmcnt(0)" ::: "memory");
    __syncthreads();

    // Epilogue: out[b][n] = sum_c pooled[n][b*256+c] * weight[n][c].
    // acc[i][j][reg] = pooled[rowBase + wr*128 + i*16 + quad*4 + reg]
    //                        [colBase + wc*64 + j*16 + m]
    float* red = (float*)lds;                // [4 wc][256 n_local]
    const int cwbase = wc * 64 + m;
#pragma unroll
    for (int i = 0; i < 8; ++i) {
#pragma unroll
        for (int reg = 0; reg < 4; ++reg) {
            const int nloc = wr * 128 + i * 16 + quad * 4 + reg;
            const float* wrow = weight + (size_t)(rowBase + nloc) * 256 + cwbase;
            float s = 0.f;
#pragma unroll
            for (int j = 0; j < 4; ++j)
                s += acc[i][j][reg] * wrow[j * 16];
            s += __shfl_xor(s, 1);
            s += __shfl_xor(s, 2);
            s += __shfl_xor(s, 4);
            s += __shfl_xor(s, 8);
            if (m == 0)
                red[wc * 256 + nloc] = s;
        }
    }
    __syncthreads();
    if (tid < 256) {
        const float s = red[tid] + red[256 + tid] + red[512 + tid] + red[768 + tid];
        out[(size_t)blockIdx.x * NG + rowBase + tid] = s;
    }
}

// ---------------------------------------------------------------------------
extern "C" void kernel_launch(void* const* d_in, const int* in_sizes, int n_in,
                              void* d_out, int out_size, void* d_ws, size_t ws_size,
                              hipStream_t stream) {
    const float* feat   = (const float*)d_in[0];
    const float* mu     = (const float*)d_in[1];
    const float* logsx  = (const float*)d_in[2];
    const float* logsy  = (const float*)d_in[3];
    const float* rho    = (const float*)d_in[4];
    const float* weight = (const float*)d_in[5];
    float* out = (float*)d_out;

    unsigned short* Gbuf = (unsigned short*)d_ws;                  // 4096*2304*2 B
    unsigned short* Fbuf = Gbuf + (size_t)NG * P_HW;               // 8192*2304*2 B

    hipLaunchKernelGGL(prep_kernel, dim3(13376), dim3(256), 0, stream,
                       feat, mu, logsx, logsy, rho, Fbuf, Gbuf, out);

    hipLaunchKernelGGL(gemm_fused, dim3(NCOL / 256, NG / 256), dim3(512), 0, stream,
                       Gbuf, Fbuf, weight, out);
}